// Round 1
// baseline (227.818 us; speedup 1.0000x reference)
//
#include <hip/hip_runtime.h>

typedef _Float16 f16;
typedef f16 f16x8 __attribute__((ext_vector_type(8)));
typedef f16 f16x4 __attribute__((ext_vector_type(4)));
typedef float f32x4 __attribute__((ext_vector_type(4)));

#define MFMA16(A, B, C) __builtin_amdgcn_mfma_f32_16x16x32_f16(A, B, C, 0, 0, 0)

// scores are q.k / sqrt(64); we also fold log2(e) so softmax uses exp2.
// Folded into q at projection time.
#define QSCALE (0.125f * 1.44269504088896340736f)

// ---------------------------------------------------------------------------
// Kernel 0: transpose + cast W matrices: Wt[n=192][k=768] f16 from W[768][64]
// rows 0-63 = Wq cols, 64-127 = Wk cols, 128-191 = Wv cols.
// ---------------------------------------------------------------------------
__global__ __launch_bounds__(256) void wtrans_kernel(
    const float* __restrict__ Wq, const float* __restrict__ Wk,
    const float* __restrict__ Wv, f16* __restrict__ Wt) {
  int gid = blockIdx.x * 256 + threadIdx.x;
  if (gid >= 3 * 64 * 768) return;
  int wsel = gid / (64 * 768);
  int rem = gid - wsel * (64 * 768);
  int nloc = rem / 768;
  int kk = rem - nloc * 768;
  const float* W = (wsel == 0) ? Wq : ((wsel == 1) ? Wk : Wv);
  Wt[gid] = (f16)W[kk * 64 + nloc];
}

// ---------------------------------------------------------------------------
// Kernel 1: projection GEMM. Each block: 64 rows x 192 cols (q|k|v).
// q = (x@Wq + bq) * QSCALE  -> qo[16384][64] f16
// k = (x@Wk + bk)           -> ko[16384][64] f16
// v = (x@Wv + bv)           -> vt[b][64][4096] f16 (TRANSPOSED per batch)
// ---------------------------------------------------------------------------
__global__ __launch_bounds__(256) void proj_kernel(
    const float* __restrict__ x, const f16* __restrict__ Wt,
    const float* __restrict__ bq, const float* __restrict__ bk,
    const float* __restrict__ bv, f16* __restrict__ qo, f16* __restrict__ ko,
    f16* __restrict__ vt) {
  // pad 32 -> 40 halves (80 B rows: 16B-aligned, 2-way bank alias = free)
  __shared__ f16 Xs[64][40];
  __shared__ f16 Ws[192][40];

  const int t = threadIdx.x;
  const int w = t >> 6;
  const int lane = t & 63;
  const int ln = lane & 15;
  const int quad = lane >> 4;
  const int r0 = blockIdx.x * 64;

  f32x4 acc[12];
#pragma unroll
  for (int i = 0; i < 12; i++) acc[i] = (f32x4){0.f, 0.f, 0.f, 0.f};

  const int srow = t >> 2;       // 0..63
  const int sc = (t & 3) * 8;    // 0,8,16,24

  for (int kc = 0; kc < 24; kc++) {
    const int k0 = kc * 32;
    // stage x chunk (64x32) fp32 -> f16 LDS
    {
      const float* xp = x + (r0 + srow) * 768 + k0 + sc;
      float4 a = *(const float4*)xp;
      float4 b2 = *(const float4*)(xp + 4);
      f16x8 h;
      h[0] = (f16)a.x; h[1] = (f16)a.y; h[2] = (f16)a.z; h[3] = (f16)a.w;
      h[4] = (f16)b2.x; h[5] = (f16)b2.y; h[6] = (f16)b2.z; h[7] = (f16)b2.w;
      *(f16x8*)&Xs[srow][sc] = h;
    }
    // stage Wt chunk (192x32) f16 LDS
#pragma unroll
    for (int p = 0; p < 3; p++) {
      int rw = p * 64 + srow;
      *(f16x8*)&Ws[rw][sc] = *(const f16x8*)(Wt + rw * 768 + k0 + sc);
    }
    __syncthreads();

    // A-frag: rows owned by this wave (m = ln), k = quad*8..+7
    f16x8 a0 = *(const f16x8*)&Xs[w * 16 + ln][quad * 8];
#pragma unroll
    for (int nt = 0; nt < 12; nt++) {
      f16x8 b0 = *(const f16x8*)&Ws[nt * 16 + ln][quad * 8];
      acc[nt] = MFMA16(a0, b0, acc[nt]);
    }
    __syncthreads();
  }

  // epilogue: C layout col = ln (+16*nt), row = quad*4 + r (+16*w)
  const int rloc = w * 16 + quad * 4;
  const int rowg = r0 + rloc;

  // q (tiles 0..3), scaled
#pragma unroll
  for (int nt = 0; nt < 4; nt++) {
    int d = nt * 16 + ln;
    float bb = bq[d];
#pragma unroll
    for (int r = 0; r < 4; r++)
      qo[(rowg + r) * 64 + d] = (f16)((acc[nt][r] + bb) * QSCALE);
  }
  // k (tiles 4..7)
#pragma unroll
  for (int nt = 0; nt < 4; nt++) {
    int d = nt * 16 + ln;
    float bb = bk[d];
#pragma unroll
    for (int r = 0; r < 4; r++)
      ko[(rowg + r) * 64 + d] = (f16)(acc[nt + 4][r] + bb);
  }
  // v (tiles 8..11), transposed store: vt[b][d][s], 4 consecutive s -> 8B
  const int bidx = r0 >> 12;
  const int sb = (r0 & 4095) + rloc;
#pragma unroll
  for (int nt = 0; nt < 4; nt++) {
    int d = nt * 16 + ln;
    float bb = bv[d];
    f16x4 hv;
#pragma unroll
    for (int r = 0; r < 4; r++) hv[r] = (f16)(acc[nt + 8][r] + bb);
    *(f16x4*)&vt[((bidx * 64 + d) << 12) + sb] = hv;
  }
}

// ---------------------------------------------------------------------------
// Kernel 2: flash attention. Block = (batch, 64-row Q tile), 4 waves.
// Each wave owns 16 Q rows: online softmax state in registers, quad-local
// shuffles for row max/sum. KV tiles of 64 keys staged in LDS.
// ---------------------------------------------------------------------------
__global__ __launch_bounds__(256) void attn_kernel(
    const f16* __restrict__ qo, const f16* __restrict__ ko,
    const f16* __restrict__ vt, float* __restrict__ out) {
  // 72-half rows: 144 B (16B-aligned), 2-way bank alias on frag reads = free
  __shared__ f16 Ksh[64][72];   // [key][d]
  __shared__ f16 Vsh[64][72];   // [d][key]  (from transposed vt)
  __shared__ f16 Psh[4][16][72]; // per-wave P: [m][key]

  const int t = threadIdx.x;
  const int w = t >> 6;
  const int lane = t & 63;
  const int ln = lane & 15;
  const int quad = lane >> 4;
  const int b = blockIdx.y;
  const int s0q = blockIdx.x * 64;

  // Q A-frags held in registers for whole kernel (pre-scaled by QSCALE)
  const int qoff = (b * 4096 + s0q + w * 16 + ln) * 64 + quad * 8;
  const f16x8 aq0 = *(const f16x8*)(qo + qoff);
  const f16x8 aq1 = *(const f16x8*)(qo + qoff + 32);

  f32x4 o[4];
#pragma unroll
  for (int i = 0; i < 4; i++) o[i] = (f32x4){0.f, 0.f, 0.f, 0.f};
  float m_r[4], l_r[4];
#pragma unroll
  for (int r = 0; r < 4; r++) { m_r[r] = -__builtin_inff(); l_r[r] = 0.f; }

  const int rr = t >> 3;        // 0..31
  const int cc = (t & 7) * 8;   // 0..56
  const f16* kbase = ko + b * 4096 * 64;
  const f16* vbase = vt + b * 64 * 4096;

  for (int kt = 0; kt < 64; kt++) {
    __syncthreads();  // protect prior iteration's LDS reads
    const int ks0 = kt * 64;
    *(f16x8*)&Ksh[rr][cc]      = *(const f16x8*)(kbase + (ks0 + rr) * 64 + cc);
    *(f16x8*)&Ksh[rr + 32][cc] = *(const f16x8*)(kbase + (ks0 + rr + 32) * 64 + cc);
    *(f16x8*)&Vsh[rr][cc]      = *(const f16x8*)(vbase + rr * 4096 + ks0 + cc);
    *(f16x8*)&Vsh[rr + 32][cc] = *(const f16x8*)(vbase + (rr + 32) * 4096 + ks0 + cc);
    __syncthreads();

    // S = Q @ K^T  (already in exp2 units: q pre-scaled)
    f32x4 s[4];
#pragma unroll
    for (int i = 0; i < 4; i++) s[i] = (f32x4){0.f, 0.f, 0.f, 0.f};
#pragma unroll
    for (int nt = 0; nt < 4; nt++) {
      f16x8 b0 = *(const f16x8*)&Ksh[nt * 16 + ln][quad * 8];
      f16x8 b1 = *(const f16x8*)&Ksh[nt * 16 + ln][32 + quad * 8];
      s[nt] = MFMA16(aq0, b0, s[nt]);
      s[nt] = MFMA16(aq1, b1, s[nt]);
    }

    // online softmax: rows owned by this quad (row = quad*4 + r)
    float al[4];
#pragma unroll
    for (int r = 0; r < 4; r++) {
      float vm = fmaxf(fmaxf(s[0][r], s[1][r]), fmaxf(s[2][r], s[3][r]));
      vm = fmaxf(vm, __shfl_xor(vm, 1));
      vm = fmaxf(vm, __shfl_xor(vm, 2));
      vm = fmaxf(vm, __shfl_xor(vm, 4));
      vm = fmaxf(vm, __shfl_xor(vm, 8));
      float mn = fmaxf(m_r[r], vm);
      al[r] = exp2f(m_r[r] - mn);
      m_r[r] = mn;
      l_r[r] *= al[r];
    }
    float pv[4][4];
#pragma unroll
    for (int nt = 0; nt < 4; nt++)
#pragma unroll
      for (int r = 0; r < 4; r++) pv[nt][r] = exp2f(s[nt][r] - m_r[r]);
#pragma unroll
    for (int r = 0; r < 4; r++) {
      float rs = (pv[0][r] + pv[1][r]) + (pv[2][r] + pv[3][r]);
      rs += __shfl_xor(rs, 1);
      rs += __shfl_xor(rs, 2);
      rs += __shfl_xor(rs, 4);
      rs += __shfl_xor(rs, 8);
      l_r[r] += rs;
    }
#pragma unroll
    for (int nt = 0; nt < 4; nt++)
#pragma unroll
      for (int r = 0; r < 4; r++) o[nt][r] *= al[r];

    // P: C-layout -> LDS -> A-layout (per-wave region, no barrier needed)
#pragma unroll
    for (int nt = 0; nt < 4; nt++)
#pragma unroll
      for (int r = 0; r < 4; r++)
        Psh[w][quad * 4 + r][nt * 16 + ln] = (f16)pv[nt][r];

    f16x8 ap0 = *(const f16x8*)&Psh[w][ln][quad * 8];
    f16x8 ap1 = *(const f16x8*)&Psh[w][ln][32 + quad * 8];
#pragma unroll
    for (int nt = 0; nt < 4; nt++) {
      f16x8 b0 = *(const f16x8*)&Vsh[nt * 16 + ln][quad * 8];
      f16x8 b1 = *(const f16x8*)&Vsh[nt * 16 + ln][32 + quad * 8];
      o[nt] = MFMA16(ap0, b0, o[nt]);
      o[nt] = MFMA16(ap1, b1, o[nt]);
    }
  }

  // epilogue: out[b][s][d] fp32
  const int orow = b * 4096 + s0q + w * 16 + quad * 4;
#pragma unroll
  for (int r = 0; r < 4; r++) {
    float inv = 1.0f / l_r[r];
#pragma unroll
    for (int nt = 0; nt < 4; nt++)
      out[(orow + r) * 64 + nt * 16 + ln] = o[nt][r] * inv;
  }
}

// ---------------------------------------------------------------------------
extern "C" void kernel_launch(void* const* d_in, const int* in_sizes, int n_in,
                              void* d_out, int out_size, void* d_ws,
                              size_t ws_size, hipStream_t stream) {
  const float* x = (const float*)d_in[0];
  const float* Wq = (const float*)d_in[1];
  const float* bq = (const float*)d_in[2];
  const float* Wk = (const float*)d_in[3];
  const float* bk = (const float*)d_in[4];
  const float* Wv = (const float*)d_in[5];
  const float* bv = (const float*)d_in[6];
  float* out = (float*)d_out;

  char* ws = (char*)d_ws;
  f16* Wt = (f16*)ws;                          // 192*768*2   = 294912 B
  f16* qo = (f16*)(ws + 294912);               // 16384*64*2  = 2 MiB
  f16* ko = (f16*)(ws + 294912 + 2097152);     // 2 MiB
  f16* vt = (f16*)(ws + 294912 + 2 * 2097152); // 2 MiB (transposed)

  wtrans_kernel<<<dim3(576), dim3(256), 0, stream>>>(Wq, Wk, Wv, Wt);
  proj_kernel<<<dim3(256), dim3(256), 0, stream>>>(x, Wt, bq, bk, bv, qo, ko, vt);
  attn_kernel<<<dim3(64, 4), dim3(256), 0, stream>>>(qo, ko, vt, out);
}

// Round 3
// 162.557 us; speedup vs baseline: 1.4015x; 1.4015x over previous
//
#include <hip/hip_runtime.h>

typedef _Float16 f16;
typedef f16 f16x8 __attribute__((ext_vector_type(8)));
typedef f16 f16x4 __attribute__((ext_vector_type(4)));
typedef float f32x4 __attribute__((ext_vector_type(4)));

#define MFMA32(A, B, C) __builtin_amdgcn_mfma_f32_16x16x32_f16(A, B, C, 0, 0, 0)
#define MFMA16(A, B, C) __builtin_amdgcn_mfma_f32_16x16x16f16(A, B, C, 0, 0, 0)

// scores = q.k / sqrt(64), folded with log2(e) into q so softmax uses exp2.
#define QSCALE (0.125f * 1.44269504088896340736f)

// ---------------------------------------------------------------------------
// Kernel 0: transpose + cast W: Wt[n=192][k=768] f16 from W[768][64] fp32.
// rows 0-63 = Wq cols, 64-127 = Wk cols, 128-191 = Wv cols.
// ---------------------------------------------------------------------------
__global__ __launch_bounds__(256) void wtrans_kernel(
    const float* __restrict__ Wq, const float* __restrict__ Wk,
    const float* __restrict__ Wv, f16* __restrict__ Wt) {
  int gid = blockIdx.x * 256 + threadIdx.x;
  if (gid >= 3 * 64 * 768) return;
  int wsel = gid / (64 * 768);
  int rem = gid - wsel * (64 * 768);
  int nloc = rem / 768;
  int kk = rem - nloc * 768;
  const float* W = (wsel == 0) ? Wq : ((wsel == 1) ? Wk : Wv);
  Wt[gid] = (f16)W[kk * 64 + nloc];
}

// ---------------------------------------------------------------------------
// Kernel 1: projection GEMM, N-SPLIT: grid (256 m-tiles, 3), blockIdx.y
// selects q / k / v (64 output cols each). 768 blocks -> 3 blocks/CU,
// 12 waves/CU (vs 4 before). x re-read x3 is L3-resident (50 MB < 256 MB).
// ---------------------------------------------------------------------------
__global__ __launch_bounds__(256, 4) void proj_kernel(
    const float* __restrict__ x, const f16* __restrict__ Wt,
    const float* __restrict__ bq, const float* __restrict__ bk,
    const float* __restrict__ bv, f16* __restrict__ qo, f16* __restrict__ ko,
    f16* __restrict__ vt) {
  // rows padded 32 -> 40 halves (80 B: 16B-aligned, 2-way bank alias = free)
  __shared__ f16 Xs[64][40];
  __shared__ f16 Ws[64][40];

  const int t = threadIdx.x;
  const int w = t >> 6;
  const int lane = t & 63;
  const int ln = lane & 15;
  const int quad = lane >> 4;
  const int r0 = blockIdx.x * 64;
  const int y = blockIdx.y;  // 0=q 1=k 2=v

  f32x4 acc[4];
#pragma unroll
  for (int i = 0; i < 4; i++) acc[i] = (f32x4){0.f, 0.f, 0.f, 0.f};

  const int srow = t >> 2;     // 0..63
  const int sc = (t & 3) * 8;  // 0,8,16,24

  for (int kc = 0; kc < 24; kc++) {
    const int k0 = kc * 32;
    {  // stage x chunk (64 rows x 32 k) fp32 -> f16
      const float* xp = x + (r0 + srow) * 768 + k0 + sc;
      float4 a = *(const float4*)xp;
      float4 b2 = *(const float4*)(xp + 4);
      f16x8 h;
      h[0] = (f16)a.x; h[1] = (f16)a.y; h[2] = (f16)a.z; h[3] = (f16)a.w;
      h[4] = (f16)b2.x; h[5] = (f16)b2.y; h[6] = (f16)b2.z; h[7] = (f16)b2.w;
      *(f16x8*)&Xs[srow][sc] = h;
    }
    // stage this split's W chunk (64 n x 32 k) f16
    *(f16x8*)&Ws[srow][sc] = *(const f16x8*)(Wt + (y * 64 + srow) * 768 + k0 + sc);
    __syncthreads();

    f16x8 a0 = *(const f16x8*)&Xs[w * 16 + ln][quad * 8];
#pragma unroll
    for (int nt = 0; nt < 4; nt++) {
      f16x8 b0 = *(const f16x8*)&Ws[nt * 16 + ln][quad * 8];
      acc[nt] = MFMA32(a0, b0, acc[nt]);
    }
    __syncthreads();
  }

  // epilogue: C layout col=ln (+16nt) = n, row=quad*4+r (+16w) = m
  const int rloc = w * 16 + quad * 4;
  const int rowg = r0 + rloc;

  if (y == 0) {  // q, pre-scaled
#pragma unroll
    for (int nt = 0; nt < 4; nt++) {
      int d = nt * 16 + ln;
      float bb = bq[d];
#pragma unroll
      for (int r = 0; r < 4; r++)
        qo[(rowg + r) * 64 + d] = (f16)((acc[nt][r] + bb) * QSCALE);
    }
  } else if (y == 1) {  // k
#pragma unroll
    for (int nt = 0; nt < 4; nt++) {
      int d = nt * 16 + ln;
      float bb = bk[d];
#pragma unroll
      for (int r = 0; r < 4; r++)
        ko[(rowg + r) * 64 + d] = (f16)(acc[nt][r] + bb);
    }
  } else {  // v, transposed store vt[b][d][s]
    const int bidx = r0 >> 12;
    const int sb = (r0 & 4095) + rloc;
#pragma unroll
    for (int nt = 0; nt < 4; nt++) {
      int d = nt * 16 + ln;
      float bb = bv[d];
      f16x4 hv;
#pragma unroll
      for (int r = 0; r < 4; r++) hv[r] = (f16)(acc[nt][r] + bb);
      *(f16x4*)&vt[((bidx * 64 + d) << 12) + sb] = hv;
    }
  }
}

// ---------------------------------------------------------------------------
// Kernel 2: flash attention, KV-SPLIT x4. Grid (64 qtiles, 4 b, 4 chunks)
// = 1024 blocks -> 4 blocks/CU, 16 waves/CU. Each block: 64 q rows x 1024
// keys, writes UNNORMALIZED partial o + per-row (m, l) for the merge pass.
//
// Transposed-score trick: St = K·Q^T (A=K-frag, B=Q-frag). C-layout gives
// St[key=quad*4+r (+16nt)][q=ln]; softmax row stats per ln need only
// xor16/xor32 shuffles, and P lands DIRECTLY in 16x16x16 A-operand layout
// (m=ln, k=quad*4+j) -> no LDS round-trip for P.
// ---------------------------------------------------------------------------
__global__ __launch_bounds__(256, 4) void attn_kernel(
    const f16* __restrict__ qo, const f16* __restrict__ ko,
    const f16* __restrict__ vt, float* __restrict__ po,
    float* __restrict__ pm, float* __restrict__ pl) {
  __shared__ f16 Ksh[64][72];  // [key][d], 144B rows (16B-aligned)
  __shared__ f16 Vsh[64][72];  // [d][key]

  const int t = threadIdx.x;
  const int w = t >> 6;
  const int lane = t & 63;
  const int ln = lane & 15;
  const int quad = lane >> 4;
  const int qt = blockIdx.x;
  const int b = blockIdx.y;
  const int c = blockIdx.z;

  // Q fragments (B-operand layout == A layout: outer=ln, k=quad*8+j)
  const int qoff = (b * 4096 + qt * 64 + w * 16 + ln) * 64 + quad * 8;
  const f16x8 bq0 = *(const f16x8*)(qo + qoff);
  const f16x8 bq1 = *(const f16x8*)(qo + qoff + 32);

  f32x4 o[4];
#pragma unroll
  for (int i = 0; i < 4; i++) o[i] = (f32x4){0.f, 0.f, 0.f, 0.f};
  float m_s = -__builtin_inff();
  float l_s = 0.f;

  const int rr = t >> 3;       // 0..31
  const int cc = (t & 7) * 8;  // 0..56
  const f16* kbase = ko + (b * 4096 + c * 1024) * 64;
  const f16* vbase = vt + b * 64 * 4096 + c * 1024;

  for (int kt = 0; kt < 16; kt++) {
    __syncthreads();  // protect prior iteration's LDS reads
    const int ks0 = kt * 64;
    *(f16x8*)&Ksh[rr][cc]      = *(const f16x8*)(kbase + (ks0 + rr) * 64 + cc);
    *(f16x8*)&Ksh[rr + 32][cc] = *(const f16x8*)(kbase + (ks0 + rr + 32) * 64 + cc);
    *(f16x8*)&Vsh[rr][cc]      = *(const f16x8*)(vbase + rr * 4096 + ks0 + cc);
    *(f16x8*)&Vsh[rr + 32][cc] = *(const f16x8*)(vbase + (rr + 32) * 4096 + ks0 + cc);
    __syncthreads();

    // St[key][q] = K · Q^T  (q pre-scaled into exp2 units)
    f32x4 st[4];
#pragma unroll
    for (int i = 0; i < 4; i++) st[i] = (f32x4){0.f, 0.f, 0.f, 0.f};
#pragma unroll
    for (int nt = 0; nt < 4; nt++) {
      f16x8 a0 = *(const f16x8*)&Ksh[nt * 16 + ln][quad * 8];
      f16x8 a1 = *(const f16x8*)&Ksh[nt * 16 + ln][32 + quad * 8];
      st[nt] = MFMA32(a0, bq0, st[nt]);
      st[nt] = MFMA32(a1, bq1, st[nt]);
    }

    // online softmax for q=ln: in-lane over 16 keys, then quads (xor16/32)
    float vmax = st[0][0];
#pragma unroll
    for (int nt = 0; nt < 4; nt++)
#pragma unroll
      for (int r = 0; r < 4; r++) vmax = fmaxf(vmax, st[nt][r]);
    vmax = fmaxf(vmax, __shfl_xor(vmax, 16));
    vmax = fmaxf(vmax, __shfl_xor(vmax, 32));
    const float mn = fmaxf(m_s, vmax);
    const float al = exp2f(m_s - mn);
    m_s = mn;

    float pv[4][4];
    float rs = 0.f;
#pragma unroll
    for (int nt = 0; nt < 4; nt++)
#pragma unroll
      for (int r = 0; r < 4; r++) {
        pv[nt][r] = exp2f(st[nt][r] - mn);
        rs += pv[nt][r];
      }
    rs += __shfl_xor(rs, 16);
    rs += __shfl_xor(rs, 32);
    l_s = l_s * al + rs;

    // rescale o rows (q = quad*4+r locally): broadcast al from lane q
    float alr[4];
#pragma unroll
    for (int r = 0; r < 4; r++) alr[r] = __shfl(al, quad * 4 + r);
#pragma unroll
    for (int dt = 0; dt < 4; dt++)
#pragma unroll
      for (int r = 0; r < 4; r++) o[dt][r] *= alr[r];

    // P is already in 16x16x16 A-layout: pack to f16
    f16x4 pa[4];
#pragma unroll
    for (int nt = 0; nt < 4; nt++)
#pragma unroll
      for (int r = 0; r < 4; r++) pa[nt][r] = (f16)pv[nt][r];

    // o[q][d] += P · V   (B-frag: V[key=quad*4+j+16nt][d=ln+16dt])
#pragma unroll
    for (int nt = 0; nt < 4; nt++)
#pragma unroll
      for (int dt = 0; dt < 4; dt++) {
        f16x4 bv = *(const f16x4*)&Vsh[dt * 16 + ln][nt * 16 + quad * 4];
        o[dt] = MFMA16(pa[nt], bv, o[dt]);
      }
  }

  // epilogue: unnormalized partial out + stats
  const int blin = (c * 4 + b) * 64 + qt;
  float* pob = po + blin * 4096;
#pragma unroll
  for (int dt = 0; dt < 4; dt++)
#pragma unroll
    for (int r = 0; r < 4; r++)
      pob[(w * 16 + quad * 4 + r) * 64 + dt * 16 + ln] = o[dt][r];
  if (quad == 0) {
    pm[blin * 64 + w * 16 + ln] = m_s;
    pl[blin * 64 + w * 16 + ln] = l_s;
  }
}

// ---------------------------------------------------------------------------
// Kernel 3: merge the 4 KV-chunks. Grid (64 qt, 4 b, 4 row-quarters).
// out = sum_c 2^(m_c-m*) o_c / sum_c 2^(m_c-m*) l_c
// ---------------------------------------------------------------------------
__global__ __launch_bounds__(256) void merge_kernel(
    const float* __restrict__ po, const float* __restrict__ pm,
    const float* __restrict__ pl, float* __restrict__ out) {
  const int qt = blockIdx.x;
  const int b = blockIdx.y;
  const int z = blockIdx.z;
  const int d = threadIdx.x & 63;
  const int qw = threadIdx.x >> 6;

#pragma unroll
  for (int q0 = 0; q0 < 4; q0++) {
    const int q = z * 16 + q0 * 4 + qw;
    float mm[4], ll[4];
#pragma unroll
    for (int c = 0; c < 4; c++) {
      const int blin = (c * 4 + b) * 64 + qt;
      mm[c] = pm[blin * 64 + q];
      ll[c] = pl[blin * 64 + q];
    }
    float ms = fmaxf(fmaxf(mm[0], mm[1]), fmaxf(mm[2], mm[3]));
    float den = 0.f, num = 0.f;
#pragma unroll
    for (int c = 0; c < 4; c++) {
      const int blin = (c * 4 + b) * 64 + qt;
      const float a = exp2f(mm[c] - ms);
      den += a * ll[c];
      num += a * po[blin * 4096 + q * 64 + d];
    }
    out[(b * 4096 + qt * 64 + q) * 64 + d] = num / den;
  }
}

// ---------------------------------------------------------------------------
extern "C" void kernel_launch(void* const* d_in, const int* in_sizes, int n_in,
                              void* d_out, int out_size, void* d_ws,
                              size_t ws_size, hipStream_t stream) {
  const float* x = (const float*)d_in[0];
  const float* Wq = (const float*)d_in[1];
  const float* bq = (const float*)d_in[2];
  const float* Wk = (const float*)d_in[3];
  const float* bk = (const float*)d_in[4];
  const float* Wv = (const float*)d_in[5];
  const float* bv = (const float*)d_in[6];
  float* out = (float*)d_out;

  char* ws = (char*)d_ws;
  f16* Wt = (f16*)ws;                              // 294912 B
  f16* qo = (f16*)(ws + 294912);                   // 2 MiB
  f16* ko = (f16*)(ws + 294912 + 2097152);         // 2 MiB
  f16* vt = (f16*)(ws + 294912 + 2 * 2097152);     // 2 MiB
  float* po = (float*)(ws + 6586368);              // 1024*4096*4 = 16 MiB
  float* pm = (float*)(ws + 6586368 + 16777216);   // 256 KiB
  float* pl = (float*)(ws + 6586368 + 16777216 + 262144);  // 256 KiB

  wtrans_kernel<<<dim3(576), dim3(256), 0, stream>>>(Wq, Wk, Wv, Wt);
  proj_kernel<<<dim3(256, 3), dim3(256), 0, stream>>>(x, Wt, bq, bk, bv, qo, ko, vt);
  attn_kernel<<<dim3(64, 4, 4), dim3(256), 0, stream>>>(qo, ko, vt, po, pm, pl);
  merge_kernel<<<dim3(64, 4, 4), dim3(256), 0, stream>>>(po, pm, pl, out);
}